// Round 1
// 190.848 us; speedup vs baseline: 1.0604x; 1.0604x over previous
//
#include <hip/hip_runtime.h>
#include <hip/hip_bf16.h>

#define BB 32
#define NN 4096
#define DDIM 64

typedef __attribute__((ext_vector_type(8)))  short bf16x8;
typedef __attribute__((ext_vector_type(16))) float f32x16;
typedef __attribute__((ext_vector_type(4)))  float f32x4;

static __device__ inline unsigned short f2bf(float x) {
  union { float f; unsigned u; } v; v.f = x;
  unsigned r = (v.u + 0x7FFFu + ((v.u >> 16) & 1u)) >> 16;   // RNE
  return (unsigned short)r;
}

// packed fp32x2 -> bf16x2 (RNE, v_cvt_pk_bf16_f32 on gfx950)
static __device__ inline unsigned pk(float a, float b) {
  union { __hip_bfloat162 h; unsigned u; } c;
  c.h = __float22bfloat162_rn(float2{a, b});
  return c.u;
}

static __device__ inline bf16x8 pack8(const float* f) {
  union { unsigned u[4]; bf16x8 v; } r;
  r.u[0] = pk(f[0], f[1]); r.u[1] = pk(f[2], f[3]);
  r.u[2] = pk(f[4], f[5]); r.u[3] = pk(f[6], f[7]);
  return r.v;
}

// ---------------------------------------------------------------------------
// proj_gemm: MFMA operands loaded DIRECTLY from fp32 global with the
// fragment's strided-dword pattern (lanes contiguous in m/n -> 128B/half-wave
// transactions), packed to bf16 in-register.
//   mat=0: Kp[k][d] = sum_n E[n][k] K[b][n][d]   (A=E, B=K)
//   mat=1: Vp[d][k] = sum_n V[b][n][d] F[n][k]   (A=V, B=F)
// NCH split-K chunks (8 preferred: 512 blocks -> 2 blocks/CU -> 2 waves/SIMD)
// + explicit register double-buffer prefetch (load t+1 before MFMA of t).
// fp32 partial stores, reduced by reduce_cvt.
// ---------------------------------------------------------------------------
template <int SA, int SB>
static __device__ inline void load_set(
    const float* __restrict__ pA, const float* __restrict__ pB, int t,
    float a0[8], float a1[8], float b0[8], float b1[8])
{
  const float* qA = pA + (long)t * 16 * SA;
  const float* qB = pB + (long)t * 16 * SB;
#pragma unroll
  for (int j = 0; j < 8; ++j) {
    a0[j] = qA[j * SA];      a1[j] = qA[j * SA + 32];
    b0[j] = qB[j * SB];      b1[j] = qB[j * SB + 32];
  }
}

static __device__ inline void mfma4(
    f32x16 acc[2][2],
    const float a0[8], const float a1[8], const float b0[8], const float b1[8])
{
  bf16x8 A0 = pack8(a0), A1 = pack8(a1);
  bf16x8 B0 = pack8(b0), B1 = pack8(b1);
  acc[0][0] = __builtin_amdgcn_mfma_f32_32x32x16_bf16(A0, B0, acc[0][0], 0, 0, 0);
  acc[0][1] = __builtin_amdgcn_mfma_f32_32x32x16_bf16(A0, B1, acc[0][1], 0, 0, 0);
  acc[1][0] = __builtin_amdgcn_mfma_f32_32x32x16_bf16(A1, B0, acc[1][0], 0, 0, 0);
  acc[1][1] = __builtin_amdgcn_mfma_f32_32x32x16_bf16(A1, B1, acc[1][1], 0, 0, 0);
}

template <int SA, int SB, int OS, int NCH>
static __device__ inline void proj_body(
    const float* __restrict__ As, const float* __restrict__ Bs,
    float* __restrict__ Cg, int mAdd, int nAdd, int chunk, int h, int lr)
{
  constexpr int CN = NN / NCH;     // n-range per chunk
  constexpr int T  = CN / 16;      // K=16 steps

  f32x16 acc[2][2];
#pragma unroll
  for (int i = 0; i < 2; ++i)
#pragma unroll
    for (int j = 0; j < 2; ++j)
#pragma unroll
      for (int q = 0; q < 16; ++q) acc[i][j][q] = 0.f;

  const int n0 = chunk * CN + h * 8;
  const float* pA = As + (long)n0 * SA + mAdd + lr;
  const float* pB = Bs + (long)n0 * SB + nAdd + lr;

  // two named register buffer sets (static indexing only — no scratch)
  float xa0[8], xa1[8], xb0[8], xb1[8];
  float ya0[8], ya1[8], yb0[8], yb1[8];

  load_set<SA, SB>(pA, pB, 0, xa0, xa1, xb0, xb1);

  for (int tt = 0; tt < T; tt += 2) {
    // prefetch t+1 into Y, then compute X (t)
    load_set<SA, SB>(pA, pB, tt + 1, ya0, ya1, yb0, yb1);
    mfma4(acc, xa0, xa1, xb0, xb1);
    // prefetch t+2 into X (wrap to 0 on last iter: redundant, discarded)
    const int tn = (tt + 2 < T) ? (tt + 2) : 0;
    load_set<SA, SB>(pA, pB, tn, xa0, xa1, xb0, xb1);
    mfma4(acc, ya0, ya1, yb0, yb1);
  }

#pragma unroll
  for (int mt = 0; mt < 2; ++mt)
#pragma unroll
    for (int nt = 0; nt < 2; ++nt)
#pragma unroll
      for (int i = 0; i < 16; ++i) {
        int ro  = (i & 3) + 8 * (i >> 2) + 4 * h;       // C/D row map
        int row = mAdd + mt * 32 + ro;
        int col = nAdd + nt * 32 + lr;
        Cg[row * OS + col] = acc[mt][nt][i];
      }
}

template <int NCH>
__global__ __launch_bounds__(256, 2) void proj_gemm(
    const float* __restrict__ Kg, const float* __restrict__ Vg,
    const float* __restrict__ Eg, const float* __restrict__ Fg,
    float* __restrict__ KpP, float* __restrict__ VpP)
{
  const int blk = blockIdx.x;
  const int chunk = blk % NCH;                    // low bits -> same-XCD E/F chunk reuse
  const int mat = (blk / NCH) & 1, b = blk / (2 * NCH);
  const int t = threadIdx.x, w = t >> 6, l = t & 63, h = l >> 5, lr = l & 31;
  const long PSTR = (long)BB * 16384;

  if (mat == 0) {
    // A=E [n][256] (m=k, wave-split), B=K[b] [n][64] (n-dim=d), C: [k][64]
    proj_body<256, 64, 64, NCH>(Eg, Kg + (long)b * NN * DDIM,
                                KpP + (long)chunk * PSTR + b * 16384,
                                w * 64, 0, chunk, h, lr);
  } else {
    // A=V[b] [n][64] (m=d), B=F [n][256] (n-dim=k, wave-split), C: [d][256]
    proj_body<64, 256, 256, NCH>(Vg + (long)b * NN * DDIM, Fg,
                                 VpP + (long)chunk * PSTR + b * 16384,
                                 0, w * 64, chunk, h, lr);
  }
}

// ---------------------------------------------------------------------------
// reduce_cvt: sum NCH fp32 partials -> bf16. blocks [0,256): Kp, [256,512): Vp.
// ---------------------------------------------------------------------------
template <int NCH>
__global__ __launch_bounds__(256) void reduce_cvt(
    const float* __restrict__ KpP, const float* __restrict__ VpP,
    unsigned short* __restrict__ Kpb, unsigned short* __restrict__ Vpb)
{
  const int blk = blockIdx.x;
  const float* src = (blk < 256) ? KpP : VpP;
  unsigned short* dst = (blk < 256) ? Kpb : Vpb;
  const long i = (long)(blk & 255) * 2048 + threadIdx.x * 8;
  float a[8];
#pragma unroll
  for (int j = 0; j < 8; ++j) a[j] = 0.f;
#pragma unroll
  for (int cch = 0; cch < NCH; ++cch) {
    const float4 p0 = *(const float4*)(src + (long)cch * (BB * 16384) + i);
    const float4 p1 = *(const float4*)(src + (long)cch * (BB * 16384) + i + 4);
    a[0] += p0.x; a[1] += p0.y; a[2] += p0.z; a[3] += p0.w;
    a[4] += p1.x; a[5] += p1.y; a[6] += p1.z; a[7] += p1.w;
  }
  unsigned short o[8];
#pragma unroll
  for (int j = 0; j < 8; ++j) o[j] = f2bf(a[j]);
  *(bf16x8*)(dst + i) = *(const bf16x8*)&o[0];
}

// ---------------------------------------------------------------------------
// stage2 (S^T, incremental PV): per block (b, 256-row group); wave w owns
// 64 rows (2 row-tiles) and full k=256.  (unchanged this round)
// ---------------------------------------------------------------------------
__global__ __launch_bounds__(256, 2) void attn2_kernel(
    const float* __restrict__ Qg, const unsigned short* __restrict__ Kpb,
    const unsigned short* __restrict__ Vpb, float* __restrict__ Og)
{
  extern __shared__ float O_lds[];          // 256 x 64 fp32 = 64 KB

  const int blk = blockIdx.x;
  const int b = blk >> 4, rg = blk & 15;
  const int t = threadIdx.x, w = t >> 6, l = t & 63;
  const int h = l >> 5, lr = l & 31;
  const int rbase = rg * 256 + w * 64;

  const unsigned short* Kp = Kpb + (long)b * 16384;   // [k=256][d=64]
  const unsigned short* Vp = Vpb + (long)b * 16384;   // [d=64][k=256]

  // ---- Q B-frags for 2 row-tiles: B[n=r(lane lr)][k=d contiguous]
  bf16x8 Bq[2][4];
#pragma unroll
  for (int rt = 0; rt < 2; ++rt)
#pragma unroll
    for (int kk = 0; kk < 4; ++kk) {
      const float* qp = Qg + ((long)b * NN + rbase + rt * 32 + lr) * 64 + kk * 16 + h * 8;
      float4 x = *(const float4*)qp;
      float4 y = *(const float4*)(qp + 4);
      union { unsigned u[4]; bf16x8 v; } r;
      r.u[0] = pk(x.x, x.y); r.u[1] = pk(x.z, x.w);
      r.u[2] = pk(y.x, y.y); r.u[3] = pk(y.z, y.w);
      Bq[rt][kk] = r.v;
    }

  f32x16 o[2][2];                           // [row-tile][d-tile]
#pragma unroll
  for (int rt = 0; rt < 2; ++rt)
#pragma unroll
    for (int dt = 0; dt < 2; ++dt)
#pragma unroll
      for (int q = 0; q < 16; ++q) o[rt][dt][q] = 0.f;
  float rowpart[2] = {0.f, 0.f};

  union UV { uint4 u; bf16x8 v; };

#pragma unroll
  for (int kt = 0; kt < 8; ++kt) {
    // Kp A-frags (shared by both row-tiles): A[m=k][d contiguous]
    bf16x8 Ak[4];
#pragma unroll
    for (int kk = 0; kk < 4; ++kk)
      Ak[kk] = *(const bf16x8*)(Kp + (long)(kt * 32 + lr) * 64 + kk * 16 + h * 8);
    // Vp A-frags for this k-chunk pair: A[m=d][k contiguous]
    bf16x8 Av[2][2];
#pragma unroll
    for (int dt = 0; dt < 2; ++dt)
#pragma unroll
      for (int kc = 0; kc < 2; ++kc)
        Av[dt][kc] = *(const bf16x8*)(Vp + (long)(dt * 32 + lr) * 256 + (kt * 2 + kc) * 16 + h * 8);

#pragma unroll
    for (int rt = 0; rt < 2; ++rt) {
      f32x16 s;
#pragma unroll
      for (int q = 0; q < 16; ++q) s[q] = 0.f;
#pragma unroll
      for (int kk = 0; kk < 4; ++kk)
        s = __builtin_amdgcn_mfma_f32_32x32x16_bf16(Ak[kk], Bq[rt][kk], s, 0, 0, 0);

      // exp(s/8) = exp2(s*log2(e)/8); no max-subtract (fp32-safe)
      float p[16];
#pragma unroll
      for (int q = 0; q < 16; ++q) p[q] = exp2f(s[q] * 0.1803368801f);
      rowpart[rt] += (((p[0] + p[1]) + (p[2] + p[3])) + ((p[4] + p[5]) + (p[6] + p[7])))
                   + (((p[8] + p[9]) + (p[10] + p[11])) + ((p[12] + p[13]) + (p[14] + p[15])));

      unsigned wv[8];
#pragma unroll
      for (int m = 0; m < 8; ++m) wv[m] = pk(p[2 * m], p[2 * m + 1]);
      // half-wave exchange: C-layout k=(q&3)+8(q>>2)+4h -> B-layout k=h*8+j
      unsigned r02 = __shfl_xor(h ? wv[0] : wv[2], 32);
      unsigned r13 = __shfl_xor(h ? wv[1] : wv[3], 32);
      unsigned r46 = __shfl_xor(h ? wv[4] : wv[6], 32);
      unsigned r57 = __shfl_xor(h ? wv[5] : wv[7], 32);
      UV c0, c1;
      if (h == 0) {
        c0.u = uint4{wv[0], wv[1], r02, r13};
        c1.u = uint4{wv[4], wv[5], r46, r57};
      } else {
        c0.u = uint4{r02, r13, wv[2], wv[3]};
        c1.u = uint4{r46, r57, wv[6], wv[7]};
      }
      // incremental PV: consume immediately, nothing stays live
      o[rt][0] = __builtin_amdgcn_mfma_f32_32x32x16_bf16(Av[0][0], c0.v, o[rt][0], 0, 0, 0);
      o[rt][0] = __builtin_amdgcn_mfma_f32_32x32x16_bf16(Av[0][1], c1.v, o[rt][0], 0, 0, 0);
      o[rt][1] = __builtin_amdgcn_mfma_f32_32x32x16_bf16(Av[1][0], c0.v, o[rt][1], 0, 0, 0);
      o[rt][1] = __builtin_amdgcn_mfma_f32_32x32x16_bf16(Av[1][1], c1.v, o[rt][1], 0, 0, 0);
    }
  }

  // ---- normalize (rowsum at lane=row) and transpose via swizzled LDS
#pragma unroll
  for (int rt = 0; rt < 2; ++rt) {
    float rowsum = rowpart[rt] + __shfl_xor(rowpart[rt], 32);
    float inv = __builtin_amdgcn_rcpf(rowsum);
    const int r = w * 64 + rt * 32 + lr;
#pragma unroll
    for (int dt = 0; dt < 2; ++dt)
#pragma unroll
      for (int qg = 0; qg < 4; ++qg) {
        f32x4 vq;
        vq[0] = o[rt][dt][qg * 4 + 0] * inv;
        vq[1] = o[rt][dt][qg * 4 + 1] * inv;
        vq[2] = o[rt][dt][qg * 4 + 2] * inv;
        vq[3] = o[rt][dt][qg * 4 + 3] * inv;
        int cd = dt * 8 + 2 * qg + h;        // d-chunk (4 dwords)
        int cp = cd ^ (r & 15);              // XOR swizzle
        *(f32x4*)&O_lds[r * 64 + cp * 4] = vq;
      }
  }
  __syncthreads();

  const long obase = ((long)b * NN + rg * 256) * 64;
#pragma unroll
  for (int i = 0; i < 16; ++i) {
    int ci = i * 256 + t;
    int rr = ci >> 4, cc = ci & 15, cp = cc ^ (rr & 15);
    *(float4*)(Og + obase + rr * 64 + cc * 4) = *(const float4*)&O_lds[rr * 64 + cp * 4];
  }
}

extern "C" void kernel_launch(void* const* d_in, const int* in_sizes, int n_in,
                              void* d_out, int out_size, void* d_ws, size_t ws_size,
                              hipStream_t stream) {
  const float* Q = (const float*)d_in[0];
  const float* K = (const float*)d_in[1];
  const float* V = (const float*)d_in[2];
  const float* E = (const float*)d_in[3];
  const float* F = (const float*)d_in[4];
  float* out = (float*)d_out;

  char* ws = (char*)d_ws;
  const long SLAB = (long)BB * 16384 * 4;     // 2 MB per chunk-slab

  hipFuncSetAttribute((const void*)attn2_kernel,
                      hipFuncAttributeMaxDynamicSharedMemorySize, 65536);

  if (ws_size >= (size_t)(16 * SLAB + (2l << 20))) {
    // NCH=8: 16 MB KpP + 16 MB VpP + 1 MB Kpb + 1 MB Vpb = 34 MB
    float*          KpP = (float*)(ws);
    float*          VpP = (float*)(ws + 8 * SLAB);
    unsigned short* Kpb = (unsigned short*)(ws + 16 * SLAB);
    unsigned short* Vpb = Kpb + 524288;

    proj_gemm<8><<<dim3(512), dim3(256), 0, stream>>>(K, V, E, F, KpP, VpP);
    reduce_cvt<8><<<dim3(512), dim3(256), 0, stream>>>(KpP, VpP, Kpb, Vpb);
    attn2_kernel<<<dim3(512), dim3(256), 65536, stream>>>(Q, Kpb, Vpb, out);
  } else {
    // fallback NCH=4 (18 MB workspace, previous layout)
    float*          KpP = (float*)(ws);
    float*          VpP = (float*)(ws + 4 * SLAB);
    unsigned short* Kpb = (unsigned short*)(ws + 8 * SLAB);
    unsigned short* Vpb = Kpb + 524288;

    proj_gemm<4><<<dim3(256), dim3(256), 0, stream>>>(K, V, E, F, KpP, VpP);
    reduce_cvt<4><<<dim3(512), dim3(256), 0, stream>>>(KpP, VpP, Kpb, Vpb);
    attn2_kernel<<<dim3(512), dim3(256), 65536, stream>>>(Q, Kpb, Vpb, out);
  }
}

// Round 2
// 184.994 us; speedup vs baseline: 1.0940x; 1.0316x over previous
//
#include <hip/hip_runtime.h>
#include <hip/hip_bf16.h>

#define BB 32
#define NN 4096
#define DDIM 64

typedef __attribute__((ext_vector_type(8)))  short bf16x8;
typedef __attribute__((ext_vector_type(16))) float f32x16;
typedef __attribute__((ext_vector_type(4)))  float f32x4;

static __device__ inline unsigned short f2bf(float x) {
  union { float f; unsigned u; } v; v.f = x;
  unsigned r = (v.u + 0x7FFFu + ((v.u >> 16) & 1u)) >> 16;   // RNE
  return (unsigned short)r;
}

// packed fp32x2 -> bf16x2 (RNE, v_cvt_pk_bf16_f32 on gfx950)
static __device__ inline unsigned pk(float a, float b) {
  union { __hip_bfloat162 h; unsigned u; } c;
  c.h = __float22bfloat162_rn(float2{a, b});
  return c.u;
}

// ---------------------------------------------------------------------------
// proj_gemm v3: block-cooperative LDS-staged pipeline.
//   mat=0: Kp[k][d] = sum_n E[n][k] K[b][n][d]   (A=BIG(E),  B=SML(K))
//   mat=1: Vp[d][k] = sum_n V[b][n][d] F[n][k]   (A=SML(V), B=BIG(F))
// Per step (32 n's): threads gather BIG tile [32 n][256 c] and SML tile
// [32 n][64 c] fp32 (coalesced 256B segments), pack bf16, ds_write in
// MFMA-fragment order [octet g = n/8][col][8 bf16]. Consume = 8 conflict-
// free ds_read_b128 + 8 MFMA per wave. Two register stage-sets (X/Y)
// issued 2 steps ahead; double-buffered LDS; 1 barrier/step.
// B-tile staged once per block (kills 4x redundant per-wave loads).
// ---------------------------------------------------------------------------
template <int MAT, int NCH>
static __device__ inline void proj_core(
    const float* __restrict__ Gbig,   // [NN][256] (E or F)
    const float* __restrict__ Gsml,   // [NN][64]  (K[b] or V[b])
    float* __restrict__ Cg,           // partial out for this (b,chunk)
    unsigned short (*lds)[10240],
    int t, int w, int l, int h, int lr, int chunk)
{
  constexpr int CN = NN / NCH;   // n-range per chunk
  constexpr int T  = CN / 32;    // 32-n steps

  const int n00 = chunk * CN;
  const float* pb = Gbig + (long)n00 * 256 + t;             // col = tid
  const float* ps = Gsml + (long)(n00 + w * 8) * 64 + l;    // col = l, octet = w

  f32x16 acc[2][2];
#pragma unroll
  for (int i = 0; i < 2; ++i)
#pragma unroll
    for (int j = 0; j < 2; ++j)
#pragma unroll
      for (int q = 0; q < 16; ++q) acc[i][j][q] = 0.f;

  float xb[32], xs[8], yb[32], ys[8];

  auto loadset = [&](float (&vb)[32], float (&vs)[8], int step) {
    const float* qb = pb + (long)step * (32 * 256);
    const float* qs = ps + (long)step * (32 * 64);
#pragma unroll
    for (int i = 0; i < 32; ++i) vb[i] = qb[(long)i * 256];
#pragma unroll
    for (int i = 0; i < 8; ++i)  vs[i] = qs[(long)i * 64];
  };

  // LDS layout (shorts): BIG frag (g*256 + col)*8, g=0..3 -> [0, 8192)
  //                      SML frag 8192 + (g*64 + col)*8  -> [8192, 10240)
  auto writeset = [&](int buf, float (&vb)[32], float (&vs)[8]) {
#pragma unroll
    for (int g = 0; g < 4; ++g) {
      union { unsigned u[4]; bf16x8 v; } r;
      r.u[0] = pk(vb[g * 8 + 0], vb[g * 8 + 1]);
      r.u[1] = pk(vb[g * 8 + 2], vb[g * 8 + 3]);
      r.u[2] = pk(vb[g * 8 + 4], vb[g * 8 + 5]);
      r.u[3] = pk(vb[g * 8 + 6], vb[g * 8 + 7]);
      *(bf16x8*)&lds[buf][(g * 256 + t) * 8] = r.v;
    }
    {
      union { unsigned u[4]; bf16x8 v; } r;
      r.u[0] = pk(vs[0], vs[1]); r.u[1] = pk(vs[2], vs[3]);
      r.u[2] = pk(vs[4], vs[5]); r.u[3] = pk(vs[6], vs[7]);
      *(bf16x8*)&lds[buf][8192 + (w * 64 + l) * 8] = r.v;
    }
  };

  auto consume = [&](int buf) {
#pragma unroll
    for (int s2 = 0; s2 < 2; ++s2) {
      const int g = s2 * 2 + h;                 // lane's K-octet
      bf16x8 B0 = *(const bf16x8*)&lds[buf][(g * 256 + w * 64 + lr) * 8];
      bf16x8 B1 = *(const bf16x8*)&lds[buf][(g * 256 + w * 64 + 32 + lr) * 8];
      bf16x8 S0 = *(const bf16x8*)&lds[buf][8192 + (g * 64 + lr) * 8];
      bf16x8 S1 = *(const bf16x8*)&lds[buf][8192 + (g * 64 + 32 + lr) * 8];
      if (MAT == 0) {   // A = BIG (m=k, wave-split), B = SML (n=d)
        acc[0][0] = __builtin_amdgcn_mfma_f32_32x32x16_bf16(B0, S0, acc[0][0], 0, 0, 0);
        acc[0][1] = __builtin_amdgcn_mfma_f32_32x32x16_bf16(B0, S1, acc[0][1], 0, 0, 0);
        acc[1][0] = __builtin_amdgcn_mfma_f32_32x32x16_bf16(B1, S0, acc[1][0], 0, 0, 0);
        acc[1][1] = __builtin_amdgcn_mfma_f32_32x32x16_bf16(B1, S1, acc[1][1], 0, 0, 0);
      } else {          // A = SML (m=d), B = BIG (n=k, wave-split)
        acc[0][0] = __builtin_amdgcn_mfma_f32_32x32x16_bf16(S0, B0, acc[0][0], 0, 0, 0);
        acc[0][1] = __builtin_amdgcn_mfma_f32_32x32x16_bf16(S0, B1, acc[0][1], 0, 0, 0);
        acc[1][0] = __builtin_amdgcn_mfma_f32_32x32x16_bf16(S1, B0, acc[1][0], 0, 0, 0);
        acc[1][1] = __builtin_amdgcn_mfma_f32_32x32x16_bf16(S1, B1, acc[1][1], 0, 0, 0);
      }
    }
  };

  loadset(xb, xs, 0);
  loadset(yb, ys, 1);

#pragma unroll 1
  for (int tt = 0; tt < T; tt += 2) {
    writeset(0, xb, xs);
    if (tt + 2 < T) loadset(xb, xs, tt + 2);
    __syncthreads();
    consume(0);
    writeset(1, yb, ys);
    if (tt + 3 < T) loadset(yb, ys, tt + 3);
    __syncthreads();
    consume(1);
  }

  const int mAdd = (MAT == 0) ? w * 64 : 0;
  const int nAdd = (MAT == 0) ? 0 : w * 64;
  const int OS   = (MAT == 0) ? 64 : 256;
#pragma unroll
  for (int mt = 0; mt < 2; ++mt)
#pragma unroll
    for (int nt = 0; nt < 2; ++nt)
#pragma unroll
      for (int i = 0; i < 16; ++i) {
        int ro  = (i & 3) + 8 * (i >> 2) + 4 * h;       // C/D row map
        int row = mAdd + mt * 32 + ro;
        int col = nAdd + nt * 32 + lr;
        Cg[row * OS + col] = acc[mt][nt][i];
      }
}

template <int NCH>
__global__ __launch_bounds__(256, 2) void proj_gemm(
    const float* __restrict__ Kg, const float* __restrict__ Vg,
    const float* __restrict__ Eg, const float* __restrict__ Fg,
    float* __restrict__ KpP, float* __restrict__ VpP)
{
  __shared__ unsigned short lds[2][10240];               // 40 KB

  const int blk = blockIdx.x;
  const int chunk = blk % NCH;                    // chunk == XCD id -> E/F chunk stays in one L2
  const int mat = (blk / NCH) & 1, b = blk / (2 * NCH);
  const int t = threadIdx.x, w = t >> 6, l = t & 63, h = l >> 5, lr = l & 31;
  const long PSTR = (long)BB * 16384;

  if (mat == 0) {
    proj_core<0, NCH>(Eg, Kg + (long)b * NN * DDIM,
                      KpP + (long)chunk * PSTR + b * 16384, lds, t, w, l, h, lr, chunk);
  } else {
    proj_core<1, NCH>(Fg, Vg + (long)b * NN * DDIM,
                      VpP + (long)chunk * PSTR + b * 16384, lds, t, w, l, h, lr, chunk);
  }
}

// ---------------------------------------------------------------------------
// reduce_cvt: sum NCH fp32 partials -> bf16. blocks [0,256): Kp, [256,512): Vp.
// ---------------------------------------------------------------------------
template <int NCH>
__global__ __launch_bounds__(256) void reduce_cvt(
    const float* __restrict__ KpP, const float* __restrict__ VpP,
    unsigned short* __restrict__ Kpb, unsigned short* __restrict__ Vpb)
{
  const int blk = blockIdx.x;
  const float* src = (blk < 256) ? KpP : VpP;
  unsigned short* dst = (blk < 256) ? Kpb : Vpb;
  const long i = (long)(blk & 255) * 2048 + threadIdx.x * 8;
  float a[8];
#pragma unroll
  for (int j = 0; j < 8; ++j) a[j] = 0.f;
#pragma unroll
  for (int cch = 0; cch < NCH; ++cch) {
    const float4 p0 = *(const float4*)(src + (long)cch * (BB * 16384) + i);
    const float4 p1 = *(const float4*)(src + (long)cch * (BB * 16384) + i + 4);
    a[0] += p0.x; a[1] += p0.y; a[2] += p0.z; a[3] += p0.w;
    a[4] += p1.x; a[5] += p1.y; a[6] += p1.z; a[7] += p1.w;
  }
  unsigned short o[8];
#pragma unroll
  for (int j = 0; j < 8; ++j) o[j] = f2bf(a[j]);
  *(bf16x8*)(dst + i) = *(const bf16x8*)&o[0];
}

// ---------------------------------------------------------------------------
// stage2 (S^T, incremental PV): unchanged this round.
// ---------------------------------------------------------------------------
__global__ __launch_bounds__(256, 2) void attn2_kernel(
    const float* __restrict__ Qg, const unsigned short* __restrict__ Kpb,
    const unsigned short* __restrict__ Vpb, float* __restrict__ Og)
{
  extern __shared__ float O_lds[];          // 256 x 64 fp32 = 64 KB

  const int blk = blockIdx.x;
  const int b = blk >> 4, rg = blk & 15;
  const int t = threadIdx.x, w = t >> 6, l = t & 63;
  const int h = l >> 5, lr = l & 31;
  const int rbase = rg * 256 + w * 64;

  const unsigned short* Kp = Kpb + (long)b * 16384;   // [k=256][d=64]
  const unsigned short* Vp = Vpb + (long)b * 16384;   // [d=64][k=256]

  // ---- Q B-frags for 2 row-tiles: B[n=r(lane lr)][k=d contiguous]
  bf16x8 Bq[2][4];
#pragma unroll
  for (int rt = 0; rt < 2; ++rt)
#pragma unroll
    for (int kk = 0; kk < 4; ++kk) {
      const float* qp = Qg + ((long)b * NN + rbase + rt * 32 + lr) * 64 + kk * 16 + h * 8;
      float4 x = *(const float4*)qp;
      float4 y = *(const float4*)(qp + 4);
      union { unsigned u[4]; bf16x8 v; } r;
      r.u[0] = pk(x.x, x.y); r.u[1] = pk(x.z, x.w);
      r.u[2] = pk(y.x, y.y); r.u[3] = pk(y.z, y.w);
      Bq[rt][kk] = r.v;
    }

  f32x16 o[2][2];                           // [row-tile][d-tile]
#pragma unroll
  for (int rt = 0; rt < 2; ++rt)
#pragma unroll
    for (int dt = 0; dt < 2; ++dt)
#pragma unroll
      for (int q = 0; q < 16; ++q) o[rt][dt][q] = 0.f;
  float rowpart[2] = {0.f, 0.f};

  union UV { uint4 u; bf16x8 v; };

#pragma unroll
  for (int kt = 0; kt < 8; ++kt) {
    // Kp A-frags (shared by both row-tiles): A[m=k][d contiguous]
    bf16x8 Ak[4];
#pragma unroll
    for (int kk = 0; kk < 4; ++kk)
      Ak[kk] = *(const bf16x8*)(Kp + (long)(kt * 32 + lr) * 64 + kk * 16 + h * 8);
    // Vp A-frags for this k-chunk pair: A[m=d][k contiguous]
    bf16x8 Av[2][2];
#pragma unroll
    for (int dt = 0; dt < 2; ++dt)
#pragma unroll
      for (int kc = 0; kc < 2; ++kc)
        Av[dt][kc] = *(const bf16x8*)(Vp + (long)(dt * 32 + lr) * 256 + (kt * 2 + kc) * 16 + h * 8);

#pragma unroll
    for (int rt = 0; rt < 2; ++rt) {
      f32x16 s;
#pragma unroll
      for (int q = 0; q < 16; ++q) s[q] = 0.f;
#pragma unroll
      for (int kk = 0; kk < 4; ++kk)
        s = __builtin_amdgcn_mfma_f32_32x32x16_bf16(Ak[kk], Bq[rt][kk], s, 0, 0, 0);

      // exp(s/8) = exp2(s*log2(e)/8); no max-subtract (fp32-safe)
      float p[16];
#pragma unroll
      for (int q = 0; q < 16; ++q) p[q] = exp2f(s[q] * 0.1803368801f);
      rowpart[rt] += (((p[0] + p[1]) + (p[2] + p[3])) + ((p[4] + p[5]) + (p[6] + p[7])))
                   + (((p[8] + p[9]) + (p[10] + p[11])) + ((p[12] + p[13]) + (p[14] + p[15])));

      unsigned wv[8];
#pragma unroll
      for (int m = 0; m < 8; ++m) wv[m] = pk(p[2 * m], p[2 * m + 1]);
      // half-wave exchange: C-layout k=(q&3)+8(q>>2)+4h -> B-layout k=h*8+j
      unsigned r02 = __shfl_xor(h ? wv[0] : wv[2], 32);
      unsigned r13 = __shfl_xor(h ? wv[1] : wv[3], 32);
      unsigned r46 = __shfl_xor(h ? wv[4] : wv[6], 32);
      unsigned r57 = __shfl_xor(h ? wv[5] : wv[7], 32);
      UV c0, c1;
      if (h == 0) {
        c0.u = uint4{wv[0], wv[1], r02, r13};
        c1.u = uint4{wv[4], wv[5], r46, r57};
      } else {
        c0.u = uint4{r02, r13, wv[2], wv[3]};
        c1.u = uint4{r46, r57, wv[6], wv[7]};
      }
      // incremental PV: consume immediately, nothing stays live
      o[rt][0] = __builtin_amdgcn_mfma_f32_32x32x16_bf16(Av[0][0], c0.v, o[rt][0], 0, 0, 0);
      o[rt][0] = __builtin_amdgcn_mfma_f32_32x32x16_bf16(Av[0][1], c1.v, o[rt][0], 0, 0, 0);
      o[rt][1] = __builtin_amdgcn_mfma_f32_32x32x16_bf16(Av[1][0], c0.v, o[rt][1], 0, 0, 0);
      o[rt][1] = __builtin_amdgcn_mfma_f32_32x32x16_bf16(Av[1][1], c1.v, o[rt][1], 0, 0, 0);
    }
  }

  // ---- normalize (rowsum at lane=row) and transpose via swizzled LDS
#pragma unroll
  for (int rt = 0; rt < 2; ++rt) {
    float rowsum = rowpart[rt] + __shfl_xor(rowpart[rt], 32);
    float inv = __builtin_amdgcn_rcpf(rowsum);
    const int r = w * 64 + rt * 32 + lr;
#pragma unroll
    for (int dt = 0; dt < 2; ++dt)
#pragma unroll
      for (int qg = 0; qg < 4; ++qg) {
        f32x4 vq;
        vq[0] = o[rt][dt][qg * 4 + 0] * inv;
        vq[1] = o[rt][dt][qg * 4 + 1] * inv;
        vq[2] = o[rt][dt][qg * 4 + 2] * inv;
        vq[3] = o[rt][dt][qg * 4 + 3] * inv;
        int cd = dt * 8 + 2 * qg + h;        // d-chunk (4 dwords)
        int cp = cd ^ (r & 15);              // XOR swizzle
        *(f32x4*)&O_lds[r * 64 + cp * 4] = vq;
      }
  }
  __syncthreads();

  const long obase = ((long)b * NN + rg * 256) * 64;
#pragma unroll
  for (int i = 0; i < 16; ++i) {
    int ci = i * 256 + t;
    int rr = ci >> 4, cc = ci & 15, cp = cc ^ (rr & 15);
    *(float4*)(Og + obase + rr * 64 + cc * 4) = *(const float4*)&O_lds[rr * 64 + cp * 4];
  }
}

extern "C" void kernel_launch(void* const* d_in, const int* in_sizes, int n_in,
                              void* d_out, int out_size, void* d_ws, size_t ws_size,
                              hipStream_t stream) {
  const float* Q = (const float*)d_in[0];
  const float* K = (const float*)d_in[1];
  const float* V = (const float*)d_in[2];
  const float* E = (const float*)d_in[3];
  const float* F = (const float*)d_in[4];
  float* out = (float*)d_out;

  char* ws = (char*)d_ws;
  const long SLAB = (long)BB * 16384 * 4;     // 2 MB per chunk-slab

  hipFuncSetAttribute((const void*)attn2_kernel,
                      hipFuncAttributeMaxDynamicSharedMemorySize, 65536);

  if (ws_size >= (size_t)(16 * SLAB + (2l << 20))) {
    // NCH=8: 16 MB KpP + 16 MB VpP + 1 MB Kpb + 1 MB Vpb = 34 MB
    float*          KpP = (float*)(ws);
    float*          VpP = (float*)(ws + 8 * SLAB);
    unsigned short* Kpb = (unsigned short*)(ws + 16 * SLAB);
    unsigned short* Vpb = Kpb + 524288;

    proj_gemm<8><<<dim3(512), dim3(256), 0, stream>>>(K, V, E, F, KpP, VpP);
    reduce_cvt<8><<<dim3(512), dim3(256), 0, stream>>>(KpP, VpP, Kpb, Vpb);
    attn2_kernel<<<dim3(512), dim3(256), 65536, stream>>>(Q, Kpb, Vpb, out);
  } else {
    // fallback NCH=4 (18 MB workspace)
    float*          KpP = (float*)(ws);
    float*          VpP = (float*)(ws + 4 * SLAB);
    unsigned short* Kpb = (unsigned short*)(ws + 8 * SLAB);
    unsigned short* Vpb = Kpb + 524288;

    proj_gemm<4><<<dim3(256), dim3(256), 0, stream>>>(K, V, E, F, KpP, VpP);
    reduce_cvt<4><<<dim3(512), dim3(256), 0, stream>>>(KpP, VpP, Kpb, Vpb);
    attn2_kernel<<<dim3(512), dim3(256), 65536, stream>>>(Q, Kpb, Vpb, out);
  }
}